// Round 21
// baseline (140.750 us; speedup 1.0000x reference)
//
#include <hip/hip_runtime.h>

// Problem constants
#define BDIM   16
#define PDIM   12
#define TDIM   4096
#define WINW   41
#define PADW   20
#define DDIM   492      // P*WIN
#define KCODES 1024

// fp8 32x32x16 MFMA, PAIRED-K layout: one ds_read_b128 per K-pair feeds the
// even-ks and odd-ks MFMAs (2 acc chains). ks=31 covers k>=496>=DDIM -> all
// zeros (kept for a uniform 16-pair loop; costs 1/32 of MFMA).
#define KS32   32                   // K-steps (16 pairs)
#define KPAIR  16
#define NT32_BYTES (KPAIR * 64 * 16)  // 16 KiB per 32-code tile (paired)

// R16/R20 lessons: per-tile barriers + read->MFMA dep = lockstep stall;
// barrier-free LDS-resident sweep fixed the barriers (95->86). R21 attacks
// the remaining serial chain: paired-K b128 reads (16/tile, each feeding 2
// MFMAs) + 2 independent acc chains -> 4 streams/SIMD. Inner live ~118 <=
// the 128-VGPR pin (prologue spill is one-time and harmless).
#define WAVES    8                   // 512-thread blocks
#define ROWS_WAVE 32
#define BMROWS   (WAVES * ROWS_WAVE) // 256 rows per block
#define MROWS    (BDIM * TDIM)       // 65536
#define NBLK     (MROWS / BMROWS)    // 256 = 1 block/CU, single round
#define NQ       4                   // codebook quarters
#define QTILES   8                   // 32-code tiles per quarter
#define QBYTES   (QTILES * NT32_BYTES)   // 128 KiB

typedef __attribute__((ext_vector_type(16))) float f32x16;
typedef __attribute__((ext_vector_type(2))) long  long2v;

// two f32 pairs -> 4 e4m3 bytes (RNE, saturating) via v_cvt_pk_fp8_f32
__device__ __forceinline__ unsigned int pack4_fp8(float a, float b, float c, float d) {
    int v = 0;
    v = __builtin_amdgcn_cvt_pk_fp8_f32(a, b, v, false);  // bytes 0,1
    v = __builtin_amdgcn_cvt_pk_fp8_f32(c, d, v, true);   // bytes 2,3
    return (unsigned int)v;
}

__device__ __forceinline__ long pack8_fp8(const float* v) {
    unsigned int lo = pack4_fp8(v[0], v[1], v[2], v[3]);
    unsigned int hi = pack4_fp8(v[4], v[5], v[6], v[7]);
    return (long)(((unsigned long long)hi << 32) | lo);
}

// Pre-format codebook into fp8 B-fragments for mfma_f32_32x32x16_fp8_fp8,
// PAIRED-K: entry e = (nt*KPAIR + kp)*64 + lane holds 16 bytes:
//   long0: B[k][n], k = kp*32 +      hi2*8 + j   (ks = 2kp)
//   long1: B[k][n], k = kp*32 + 16 + hi2*8 + j   (ks = 2kp+1)
//   n = nt*32 + (lane&31), hi2 = lane>>5.
__global__ __launch_bounds__(256) void prep_bfrag_k(const float* __restrict__ cb,
                                                    long2v* __restrict__ bfrag) {
    int e    = blockIdx.x * 256 + threadIdx.x;   // 0..32767
    int lane = e & 63;
    int kp   = (e >> 6) & (KPAIR - 1);
    int nt   = e >> 10;
    int n    = nt * 32 + (lane & 31);
    int hi2  = lane >> 5;
    float v0[8], v1[8];
#pragma unroll
    for (int j = 0; j < 8; ++j) {
        int k0 = kp * 32 + hi2 * 8 + j;
        int k1 = k0 + 16;
        v0[j] = (k0 < DDIM) ? cb[n * DDIM + k0] : 0.f;
        v1[j] = (k1 < DDIM) ? cb[n * DDIM + k1] : 0.f;
    }
    long2v out;
    out[0] = pack8_fp8(v0);
    out[1] = pack8_fp8(v1);
    bfrag[e] = out;
}

// Exact fp32 code norms.
__global__ __launch_bounds__(64) void prep_cnorm_k(const float* __restrict__ cb,
                                                   float* __restrict__ cnorm) {
    int n = blockIdx.x;
    int lane = threadIdx.x;
    float s = 0.f;
    for (int d = lane; d < DDIM; d += 64) { float c = cb[n * DDIM + d]; s += c * c; }
#pragma unroll
    for (int m = 1; m < 64; m <<= 1) s += __shfl_xor(s, m, 64);
    if (lane == 0) cnorm[n] = s;
}

// Exact sum of ||f||^2 over all rows via window multiplicity:
// mult(tt) = 41 - max(0,20-tt) - max(0,tt-4075).
__global__ __launch_bounds__(256) void xsq_k(const float* __restrict__ x,
                                             float* __restrict__ xsq_part) {
    float s = 0.f;
    for (int i = blockIdx.x * 256 + threadIdx.x; i < BDIM * PDIM * TDIM; i += 256 * 256) {
        int tt = i & (TDIM - 1);
        int mult = WINW - max(0, PADW - tt) - max(0, tt - (TDIM - 1 - PADW));
        float v = x[i];
        s += (float)mult * v * v;
    }
#pragma unroll
    for (int m = 1; m < 64; m <<= 1) s += __shfl_xor(s, m, 64);
    __shared__ float sm[4];
    if ((threadIdx.x & 63) == 0) sm[threadIdx.x >> 6] = s;
    __syncthreads();
    if (threadIdx.x == 0) xsq_part[blockIdx.x] = sm[0] + sm[1] + sm[2] + sm[3];
}

// Stage one 128 KiB quarter into LDS: 16 global_load_lds per wave.
__device__ __forceinline__ void stage_quarter(const unsigned char* __restrict__ gq,
                                              unsigned char* smem, int wave, int lane) {
#pragma unroll
    for (int i = 0; i < 16; ++i) {
        int off = i * 8192 + wave * 1024;
        __builtin_amdgcn_global_load_lds(
            (const __attribute__((address_space(1))) unsigned int*)(gq + off + lane * 16),
            (__attribute__((address_space(3))) unsigned int*)(smem + off),
            16, 0, 0);
    }
}

// Main sweep: 256 blocks (1/CU) x 8 waves x 32 rows, single round.
// Prologue: stage quarter 0 + sb table + A-build (once) + one sync. Then 4x
// { barrier-free sweep (8 tiles x 16 b128-pair reads x 2-chain MFMAs, zero
// sync inside); sync; restage; sync }. Inner live ~118 regs.
__global__ __launch_bounds__(512)
void vq_main_k(const float* __restrict__ x,
               const unsigned char* __restrict__ bfrag,
               const float* __restrict__ cnorm,
               float* __restrict__ bpart) {
    __shared__ __align__(16) unsigned char smem[QBYTES];   // 128 KiB
    __shared__ float sb_lds[KCODES];                       // 4 KiB
    __shared__ float gsum[2 * WAVES];

    const int lane = threadIdx.x & 63;
    const int wave = threadIdx.x >> 6;
    const int col  = lane & 31;     // B/D column within tile
    const int hi2  = lane >> 5;
    const int rowbase = blockIdx.x * BMROWS + wave * ROWS_WAVE;

    // Stage quarter 0; latency covered by sb-table + A-build below.
    stage_quarter(bfrag, smem, wave, lane);

    // Full bias table: sb_lds[n] = -0.5*||c_n||^2
    for (int i = threadIdx.x; i < KCODES; i += 512)
        sb_lds[i] = -0.5f * cnorm[i];

    // ---- Build fp8 A-slab ONCE: row = rowbase + col, k = ks*16+hi2*8+j ----
    long afr[KS32];
    {
        int row = rowbase + col;
        int b = row >> 12;
        int t = row & (TDIM - 1);
        const float* xb = x + (size_t)b * (PDIM * TDIM);
#pragma unroll
        for (int ks = 0; ks < KS32; ++ks) {
            float v[8];
#pragma unroll
            for (int j = 0; j < 8; ++j) {
                int d = ks * 16 + hi2 * 8 + j;
                float f = 0.f;
                if (d < DDIM) {
                    int p  = d / WINW;
                    int w  = d - p * WINW;
                    int tt = t + w - PADW;
                    if (tt >= 0 && tt < TDIM) f = xb[p * TDIM + tt];
                }
                v[j] = f;
            }
            afr[ks] = pack8_fp8(v);
        }
    }

    f32x16 bs;
#pragma unroll
    for (int r = 0; r < 16; ++r) bs[r] = -3.0e38f;

    // Entry drain: quarter 0 resident; sb_lds visible.
    __syncthreads();

    for (int q = 0; q < NQ; ++q) {
        // ---- Barrier-free sweep of the resident quarter ----
        for (int tl = 0; tl < QTILES; ++tl) {
            const long2v* bp = (const long2v*)(smem + tl * NT32_BYTES) + lane;
            f32x16 accA, accB;   // 2 independent chains
#pragma unroll
            for (int r = 0; r < 16; ++r) { accA[r] = 0.f; accB[r] = 0.f; }
#pragma unroll
            for (int kp = 0; kp < KPAIR; ++kp) {
                long2v bq = bp[kp * 64];   // ds_read_b128: ks=2kp, 2kp+1
                accA = __builtin_amdgcn_mfma_f32_32x32x16_fp8_fp8(afr[2 * kp],     bq[0], accA, 0, 0, 0);
                accB = __builtin_amdgcn_mfma_f32_32x32x16_fp8_fp8(afr[2 * kp + 1], bq[1], accB, 0, 0, 0);
            }
            const float sb = sb_lds[q * (KCODES / NQ) + tl * 32 + col];
#pragma unroll
            for (int r = 0; r < 16; ++r)
                bs[r] = fmaxf(bs[r], accA[r] + accB[r] + sb);
        }
        // ---- Restage next quarter (2 barriers per transition) ----
        if (q + 1 < NQ) {
            __syncthreads();   // all waves done reading smem
            stage_quarter(bfrag + (size_t)(q + 1) * QBYTES, smem, wave, lane);
            __syncthreads();   // drains vmcnt(0): next quarter resident
        }
    }

    // ---- Per-row max across the 32 col-lanes (masks<32 preserve hi2) ----
#pragma unroll
    for (int m = 1; m < 32; m <<= 1)
#pragma unroll
        for (int r = 0; r < 16; ++r)
            bs[r] = fmaxf(bs[r], __shfl_xor(bs[r], m, 64));

    // D rows: row = (r&3) + 8*(r>>2) + 4*hi2 — bijective over the 32-row
    // slab; sum over all rows is mapping-invariant.
    if (col == 0) {
        float s = 0.f;
#pragma unroll
        for (int r = 0; r < 16; ++r) s += bs[r];
        gsum[wave * 2 + hi2] = s;
    }
    __syncthreads();
    if (threadIdx.x == 0) {
        float tot = 0.f;
#pragma unroll
        for (int i = 0; i < 2 * WAVES; ++i) tot += gsum[i];
        bpart[blockIdx.x] = tot;
    }
}

// loss = 0.25 * (Sxx - 2*sum_blocks bpart) / (65536*492)
__global__ __launch_bounds__(256) void finalize_k(const float* __restrict__ bpart,
                                                  const float* __restrict__ xsq_part,
                                                  float* __restrict__ out) {
    __shared__ double sm[256];
    int tid = threadIdx.x;
    sm[tid] = (double)bpart[tid];
    __syncthreads();
    for (int st = 128; st > 0; st >>= 1) {
        if (tid < st) sm[tid] += sm[tid + st];
        __syncthreads();
    }
    double S1 = sm[0];
    __syncthreads();
    sm[tid] = (double)xsq_part[tid];
    __syncthreads();
    for (int st = 128; st > 0; st >>= 1) {
        if (tid < st) sm[tid] += sm[tid + st];
        __syncthreads();
    }
    if (tid == 0)
        out[0] = (float)(0.25 * (sm[0] - 2.0 * S1) / ((double)MROWS * (double)DDIM));
}

extern "C" void kernel_launch(void* const* d_in, const int* in_sizes, int n_in,
                              void* d_out, int out_size, void* d_ws, size_t ws_size,
                              hipStream_t stream) {
    const float* x  = (const float*)d_in[0];   // (16,12,4096) f32
    const float* cb = (const float*)d_in[1];   // (1024,492) f32
    float* out = (float*)d_out;

    // workspace layout (~524 KiB)
    char* ws = (char*)d_ws;
    long2v* bfrag   = (long2v*)ws;                                  // 512 KiB
    float* cnorm    = (float*)(ws + (512u << 10));                  // 4 KiB
    float* xsq_part = (float*)(ws + (512u << 10) + 4096);           // 1 KiB
    float* bpart    = (float*)(ws + (512u << 10) + 8192);           // 1 KiB

    prep_bfrag_k<<<128, 256, 0, stream>>>(cb, bfrag);
    prep_cnorm_k<<<KCODES, 64, 0, stream>>>(cb, cnorm);
    xsq_k<<<256, 256, 0, stream>>>(x, xsq_part);
    vq_main_k<<<NBLK, 512, 0, stream>>>(x, (const unsigned char*)bfrag, cnorm, bpart);
    finalize_k<<<1, 256, 0, stream>>>(bpart, xsq_part, out);
}

// Round 22
// 72.456 us; speedup vs baseline: 1.9426x; 1.9426x over previous
//
#include <hip/hip_runtime.h>

// Problem constants
#define BDIM   16
#define PDIM   12
#define TDIM   4096
#define WINW   41
#define PADW   20
#define DDIM   492      // P*WIN
#define KCODES 1024

// fp8 32x32x16 MFMA. Tiles laid out with 32 K-steps (16 KiB); step 31 covers
// k in [496,512) >= DDIM -> all zeros -> skip (KSU=31).
#define KS32   32
#define KSU    31
#define NT32_BYTES (KS32 * 64 * 8)  // 16 KiB per 32-code tile

// R20 (86us steady): barrier-free LDS-resident-quarter sweep, A built once.
// R21 lesson: 2nd acc chain -> inner live ~120 -> in-loop spill (FETCH 120MB),
// and R11-vs-R14 showed the acc dep is NOT the limiter. R20's limiter is the
// just-in-time ds_read_b64 (~120cyc lgkmcnt) per MFMA (per-wave period ~184
// cyc). R22: depth-2 ROTATING prefetch (b0,b1; +4-6 regs, live ~114) -- the
// read is issued 2 MFMAs (~78cyc) ahead, hiding LDS latency; single acc
// chain preserved.
#define WAVES    8                   // 512-thread blocks
#define ROWS_WAVE 32
#define BMROWS   (WAVES * ROWS_WAVE) // 256 rows per block
#define MROWS    (BDIM * TDIM)       // 65536
#define NBLK     (MROWS / BMROWS)    // 256 = 1 block/CU, single round
#define NQ       4                   // codebook quarters
#define QTILES   8                   // 32-code tiles per quarter
#define QBYTES   (QTILES * NT32_BYTES)   // 128 KiB

typedef __attribute__((ext_vector_type(16))) float f32x16;

// two f32 pairs -> 4 e4m3 bytes (RNE, saturating) via v_cvt_pk_fp8_f32
__device__ __forceinline__ unsigned int pack4_fp8(float a, float b, float c, float d) {
    int v = 0;
    v = __builtin_amdgcn_cvt_pk_fp8_f32(a, b, v, false);  // bytes 0,1
    v = __builtin_amdgcn_cvt_pk_fp8_f32(c, d, v, true);   // bytes 2,3
    return (unsigned int)v;
}

// Pre-format codebook into fp8 B-fragments for mfma_f32_32x32x16_fp8_fp8.
// frag idx = (nt*KS32 + ks)*64 + lane, 8 bytes each:
//   B[k][n], n = nt*32 + (lane&31), k = ks*16 + (lane>>5)*8 + j  (byte j)
__global__ __launch_bounds__(256) void prep_bfrag_k(const float* __restrict__ cb,
                                                    unsigned long long* __restrict__ bfrag) {
    int idx  = blockIdx.x * 256 + threadIdx.x;   // 0..65535
    int lane = idx & 63;
    int ks   = (idx >> 6) & (KS32 - 1);
    int nt   = idx >> 11;
    int n    = nt * 32 + (lane & 31);
    int hi2  = lane >> 5;
    float v[8];
#pragma unroll
    for (int j = 0; j < 8; ++j) {
        int k = ks * 16 + hi2 * 8 + j;
        v[j] = (k < DDIM) ? cb[n * DDIM + k] : 0.f;
    }
    unsigned int lo = pack4_fp8(v[0], v[1], v[2], v[3]);
    unsigned int hi = pack4_fp8(v[4], v[5], v[6], v[7]);
    bfrag[idx] = ((unsigned long long)hi << 32) | lo;
}

// Exact fp32 code norms.
__global__ __launch_bounds__(64) void prep_cnorm_k(const float* __restrict__ cb,
                                                   float* __restrict__ cnorm) {
    int n = blockIdx.x;
    int lane = threadIdx.x;
    float s = 0.f;
    for (int d = lane; d < DDIM; d += 64) { float c = cb[n * DDIM + d]; s += c * c; }
#pragma unroll
    for (int m = 1; m < 64; m <<= 1) s += __shfl_xor(s, m, 64);
    if (lane == 0) cnorm[n] = s;
}

// Exact sum of ||f||^2 over all rows via window multiplicity:
// mult(tt) = 41 - max(0,20-tt) - max(0,tt-4075).
__global__ __launch_bounds__(256) void xsq_k(const float* __restrict__ x,
                                             float* __restrict__ xsq_part) {
    float s = 0.f;
    for (int i = blockIdx.x * 256 + threadIdx.x; i < BDIM * PDIM * TDIM; i += 256 * 256) {
        int tt = i & (TDIM - 1);
        int mult = WINW - max(0, PADW - tt) - max(0, tt - (TDIM - 1 - PADW));
        float v = x[i];
        s += (float)mult * v * v;
    }
#pragma unroll
    for (int m = 1; m < 64; m <<= 1) s += __shfl_xor(s, m, 64);
    __shared__ float sm[4];
    if ((threadIdx.x & 63) == 0) sm[threadIdx.x >> 6] = s;
    __syncthreads();
    if (threadIdx.x == 0) xsq_part[blockIdx.x] = sm[0] + sm[1] + sm[2] + sm[3];
}

// Stage one 128 KiB quarter into LDS: 16 global_load_lds per wave.
__device__ __forceinline__ void stage_quarter(const unsigned char* __restrict__ gq,
                                              unsigned char* smem, int wave, int lane) {
#pragma unroll
    for (int i = 0; i < 16; ++i) {
        int off = i * 8192 + wave * 1024;
        __builtin_amdgcn_global_load_lds(
            (const __attribute__((address_space(1))) unsigned int*)(gq + off + lane * 16),
            (__attribute__((address_space(3))) unsigned int*)(smem + off),
            16, 0, 0);
    }
}

// Main sweep: 256 blocks (1/CU) x 8 waves x 32 rows, single round.
// Prologue: stage quarter 0 + sb table + A-build (once) + one sync. Then 4x
// { barrier-free sweep (8 tiles x 31 MFMAs, depth-2 rotating B-prefetch,
// zero sync inside); sync; restage; sync }.
__global__ __launch_bounds__(512)
void vq_main_k(const float* __restrict__ x,
               const unsigned char* __restrict__ bfrag,
               const float* __restrict__ cnorm,
               float* __restrict__ bpart) {
    __shared__ __align__(16) unsigned char smem[QBYTES];   // 128 KiB
    __shared__ float sb_lds[KCODES];                       // 4 KiB
    __shared__ float gsum[2 * WAVES];

    const int lane = threadIdx.x & 63;
    const int wave = threadIdx.x >> 6;
    const int col  = lane & 31;     // B/D column within tile
    const int hi2  = lane >> 5;
    const int rowbase = blockIdx.x * BMROWS + wave * ROWS_WAVE;

    // Stage quarter 0; latency covered by sb-table + A-build below.
    stage_quarter(bfrag, smem, wave, lane);

    // Full bias table: sb_lds[n] = -0.5*||c_n||^2
    for (int i = threadIdx.x; i < KCODES; i += 512)
        sb_lds[i] = -0.5f * cnorm[i];

    // ---- Build fp8 A-slab ONCE: row = rowbase + col, k = ks*16+hi2*8+j ----
    long afr[KSU];
    {
        int row = rowbase + col;
        int b = row >> 12;
        int t = row & (TDIM - 1);
        const float* xb = x + (size_t)b * (PDIM * TDIM);
#pragma unroll
        for (int ks = 0; ks < KSU; ++ks) {
            float v[8];
#pragma unroll
            for (int j = 0; j < 8; ++j) {
                int d = ks * 16 + hi2 * 8 + j;
                float f = 0.f;
                if (d < DDIM) {
                    int p  = d / WINW;
                    int w  = d - p * WINW;
                    int tt = t + w - PADW;
                    if (tt >= 0 && tt < TDIM) f = xb[p * TDIM + tt];
                }
                v[j] = f;
            }
            unsigned int lo = pack4_fp8(v[0], v[1], v[2], v[3]);
            unsigned int hi = pack4_fp8(v[4], v[5], v[6], v[7]);
            afr[ks] = (long)(((unsigned long long)hi << 32) | lo);
        }
    }

    f32x16 bs;
#pragma unroll
    for (int r = 0; r < 16; ++r) bs[r] = -3.0e38f;

    // Entry drain: quarter 0 resident; sb_lds visible.
    __syncthreads();

    for (int q = 0; q < NQ; ++q) {
        // ---- Barrier-free sweep with depth-2 rotating B prefetch ----
        for (int tl = 0; tl < QTILES; ++tl) {
            const long* bp = (const long*)(smem + tl * NT32_BYTES) + lane;
            f32x16 acc;
#pragma unroll
            for (int r = 0; r < 16; ++r) acc[r] = 0.f;

            long b0 = bp[0];
            long b1 = bp[64];
#pragma unroll
            for (int ks = 0; ks < KSU; ++ks) {
                long nx = 0;
                if (ks + 2 < KSU) nx = bp[(ks + 2) * 64];   // compile-time guard
                acc = __builtin_amdgcn_mfma_f32_32x32x16_fp8_fp8(afr[ks], b0, acc, 0, 0, 0);
                b0 = b1;
                b1 = nx;
            }
            const float sb = sb_lds[q * (KCODES / NQ) + tl * 32 + col];
#pragma unroll
            for (int r = 0; r < 16; ++r)
                bs[r] = fmaxf(bs[r], acc[r] + sb);
        }
        // ---- Restage next quarter (2 barriers per transition) ----
        if (q + 1 < NQ) {
            __syncthreads();   // all waves done reading smem
            stage_quarter(bfrag + (size_t)(q + 1) * QBYTES, smem, wave, lane);
            __syncthreads();   // drains vmcnt(0): next quarter resident
        }
    }

    // ---- Per-row max across the 32 col-lanes (masks<32 preserve hi2) ----
#pragma unroll
    for (int m = 1; m < 32; m <<= 1)
#pragma unroll
        for (int r = 0; r < 16; ++r)
            bs[r] = fmaxf(bs[r], __shfl_xor(bs[r], m, 64));

    // D rows: row = (r&3) + 8*(r>>2) + 4*hi2 — bijective over the 32-row
    // slab; sum over all rows is mapping-invariant.
    if (col == 0) {
        float s = 0.f;
#pragma unroll
        for (int r = 0; r < 16; ++r) s += bs[r];
        gsum[wave * 2 + hi2] = s;
    }
    __syncthreads();
    if (threadIdx.x == 0) {
        float tot = 0.f;
#pragma unroll
        for (int i = 0; i < 2 * WAVES; ++i) tot += gsum[i];
        bpart[blockIdx.x] = tot;
    }
}

// loss = 0.25 * (Sxx - 2*sum_blocks bpart) / (65536*492)
__global__ __launch_bounds__(256) void finalize_k(const float* __restrict__ bpart,
                                                  const float* __restrict__ xsq_part,
                                                  float* __restrict__ out) {
    __shared__ double sm[256];
    int tid = threadIdx.x;
    sm[tid] = (double)bpart[tid];
    __syncthreads();
    for (int st = 128; st > 0; st >>= 1) {
        if (tid < st) sm[tid] += sm[tid + st];
        __syncthreads();
    }
    double S1 = sm[0];
    __syncthreads();
    sm[tid] = (double)xsq_part[tid];
    __syncthreads();
    for (int st = 128; st > 0; st >>= 1) {
        if (tid < st) sm[tid] += sm[tid + st];
        __syncthreads();
    }
    if (tid == 0)
        out[0] = (float)(0.25 * (sm[0] - 2.0 * S1) / ((double)MROWS * (double)DDIM));
}

extern "C" void kernel_launch(void* const* d_in, const int* in_sizes, int n_in,
                              void* d_out, int out_size, void* d_ws, size_t ws_size,
                              hipStream_t stream) {
    const float* x  = (const float*)d_in[0];   // (16,12,4096) f32
    const float* cb = (const float*)d_in[1];   // (1024,492) f32
    float* out = (float*)d_out;

    // workspace layout (~524 KiB)
    char* ws = (char*)d_ws;
    unsigned long long* bfrag = (unsigned long long*)ws;            // 512 KiB
    float* cnorm    = (float*)(ws + (512u << 10));                  // 4 KiB
    float* xsq_part = (float*)(ws + (512u << 10) + 4096);           // 1 KiB
    float* bpart    = (float*)(ws + (512u << 10) + 8192);           // 1 KiB

    prep_bfrag_k<<<256, 256, 0, stream>>>(cb, bfrag);
    prep_cnorm_k<<<KCODES, 64, 0, stream>>>(cb, cnorm);
    xsq_k<<<256, 256, 0, stream>>>(x, xsq_part);
    vq_main_k<<<NBLK, 512, 0, stream>>>(x, (const unsigned char*)bfrag, cnorm, bpart);
    finalize_k<<<1, 256, 0, stream>>>(bpart, xsq_part, out);
}